// Round 5
// baseline (205.281 us; speedup 1.0000x reference)
//
#include <hip/hip_runtime.h>
#include <hip/hip_bf16.h>

#define B_ 2
#define S_ 2048
#define E_ 1024
#define H_ 16
#define D_ 64
#define M_ (B_*S_)   // 4096 rows

typedef unsigned short u16;
typedef __attribute__((ext_vector_type(8))) short short8;   // 8 bf16 (4 VGPRs)
typedef __attribute__((ext_vector_type(4))) short short4v;  // 4 bf16 (8 B)
typedef __attribute__((ext_vector_type(4))) float f32x4;    // 4 fp32 acc

__device__ __forceinline__ float b2f(u16 u) {
    union { float f; unsigned int i; } x; x.i = ((unsigned int)u) << 16; return x.f;
}
__device__ __forceinline__ u16 f2b(float f) {
    union { float f; unsigned int i; } x; x.f = f;
    unsigned int r = x.i + 0x7fffu + ((x.i >> 16) & 1u);   // RNE
    return (u16)(r >> 16);
}
__device__ __forceinline__ int imin(int a, int b) { return a < b ? a : b; }

// ---------------- fp32 -> bf16 bulk cast (X + 4 weight matrices) ----------------
__global__ __launch_bounds__(256)
void cvt_kernel(const float* __restrict__ X,
                const float* __restrict__ Wq, const float* __restrict__ Wk,
                const float* __restrict__ Wv, const float* __restrict__ Wo,
                u16* __restrict__ Xb, u16* __restrict__ Wqb, u16* __restrict__ Wkb,
                u16* __restrict__ Wvb, u16* __restrict__ Wob)
{
    int bid = blockIdx.x;
    const float* src; u16* dst; int blk;
    if (bid < 4096) { src = X; dst = Xb; blk = bid; }
    else {
        int w = (bid - 4096) >> 10;
        blk = (bid - 4096) & 1023;
        src = (w == 0) ? Wq : (w == 1) ? Wk : (w == 2) ? Wv : Wo;
        dst = (w == 0) ? Wqb : (w == 1) ? Wkb : (w == 2) ? Wvb : Wob;
    }
    size_t i4 = (size_t)blk * 256 + threadIdx.x;     // float4 index
    float4 v = ((const float4*)src)[i4];
    short4v o;
    o.x = (short)f2b(v.x); o.y = (short)f2b(v.y);
    o.z = (short)f2b(v.z); o.w = (short)f2b(v.w);
    *(short4v*)(dst + i4 * 4) = o;
}

// ---------------- GEMM: C[M,N] = A[M,K] @ B[N,K]^T (+ optional skip) ----------------
// LDS tile: unpadded rows of 32 shorts (64 B = 4 x 16B slots).
// XOR swizzle: chunk c of row r stored at slot c ^ ((r>>1)&3) -- makes the
// lane-linear global_load_lds DMA layout give 2-way-max bank conflicts on
// the ds_read_b128 fragment reads (2-way is free, m136).
#define BM 128
#define BN 128
#define BK 32

__device__ __forceinline__ void stage2(const u16* __restrict__ gbase, u16* lds,
                                       int ldg, int wave, int lane)
{
    #pragma unroll
    for (int n = 0; n < 2; ++n) {
        int chunk = wave * 2 + n;            // 8 chunks of 16 rows; wave w: 2w, 2w+1
        int r = chunk * 16 + (lane >> 2);
        int slot = lane & 3;
        int c = slot ^ ((r >> 1) & 3);
        const u16* g = gbase + (size_t)r * ldg + c * 8;
        u16* l = lds + chunk * 512;          // wave-uniform base; HW adds lane*16B
        __builtin_amdgcn_global_load_lds(
            (const __attribute__((address_space(1))) unsigned int*)g,
            (__attribute__((address_space(3))) unsigned int*)l, 16, 0, 0);
    }
}

template<bool F32OUT>
__device__ __forceinline__ void gemm_bt_core(
    const u16* __restrict__ A, const u16* __restrict__ Bm,
    void* __restrict__ Cv, const u16* __restrict__ skip,
    int N, int Kd, int bm, int bn)
{
    __shared__ u16 lA[BM * BK];
    __shared__ u16 lB[BN * BK];
    const int tid  = threadIdx.x;
    const int wave = tid >> 6, lane = tid & 63;
    const int quad = lane >> 4, l16 = lane & 15;
    const int wm = (wave & 1) * 64, wn = (wave >> 1) * 64;

    f32x4 acc[4][4];
    #pragma unroll
    for (int i = 0; i < 4; ++i)
        #pragma unroll
        for (int j = 0; j < 4; ++j)
            acc[i][j] = (f32x4){0.f, 0.f, 0.f, 0.f};

    for (int k0 = 0; k0 < Kd; k0 += BK) {
        stage2(A  + (size_t)bm * Kd + k0, lA, Kd, wave, lane);
        stage2(Bm + (size_t)bn * Kd + k0, lB, Kd, wave, lane);
        __syncthreads();
        short8 af[4], bf[4];
        #pragma unroll
        for (int i = 0; i < 4; ++i) {
            int R = wm + i * 16 + l16;
            af[i] = *(const short8*)&lA[R * 32 + ((quad ^ ((R >> 1) & 3)) * 8)];
        }
        #pragma unroll
        for (int j = 0; j < 4; ++j) {
            int R = wn + j * 16 + l16;
            bf[j] = *(const short8*)&lB[R * 32 + ((quad ^ ((R >> 1) & 3)) * 8)];
        }
        #pragma unroll
        for (int i = 0; i < 4; ++i)
            #pragma unroll
            for (int j = 0; j < 4; ++j)
                acc[i][j] = __builtin_amdgcn_mfma_f32_16x16x32_bf16(af[i], bf[j], acc[i][j], 0, 0, 0);
        __syncthreads();
    }

    // epilogue: C/D layout col=lane&15, row=quad*4+reg
    #pragma unroll
    for (int i = 0; i < 4; ++i) {
        #pragma unroll
        for (int j = 0; j < 4; ++j) {
            int row0 = bm + wm + i * 16 + quad * 4;
            int col  = bn + wn + j * 16 + l16;
            #pragma unroll
            for (int r = 0; r < 4; ++r) {
                size_t idx = (size_t)(row0 + r) * N + col;
                float v = acc[i][j][r];
                if (skip) v += b2f(skip[idx]);
                if (F32OUT) ((float*)Cv)[idx] = v;
                else        ((u16*)Cv)[idx]   = f2b(v);
            }
        }
    }
}

__global__ __launch_bounds__(256, 3)
void qkv_kernel(const u16* __restrict__ X,
                const u16* __restrict__ Wq, const u16* __restrict__ Wk, const u16* __restrict__ Wv,
                u16* __restrict__ Q, u16* __restrict__ K, u16* __restrict__ V)
{
    const u16* W = (blockIdx.z == 0) ? Wq : (blockIdx.z == 1) ? Wk : Wv;
    u16* C = (blockIdx.z == 0) ? Q : (blockIdx.z == 1) ? K : V;
    gemm_bt_core<false>(X, W, C, nullptr, E_, E_, blockIdx.x * BM, blockIdx.y * BN);
}

__global__ __launch_bounds__(256, 3)
void out_kernel(const u16* __restrict__ An, const u16* __restrict__ Wo,
                const u16* __restrict__ V, float* __restrict__ Out)
{
    gemm_bt_core<true>(An, Wo, Out, V, E_, E_, blockIdx.x * BM, blockIdx.y * BN);
}

// ---------------- attention: diag of causal softmax ----------------
// Block = strip pair (p, 127-p) of one bh; 4 waves split the 129 t-tiles
// (ti % 4 == wave), partial (l,d) sums combined via LDS (exact: plain sums,
// logits std ~0.25 so no max subtraction needed). 2048 blocks = 8/CU.
// Software pipeline: distance-2 prefetch, ping-pong K-frag buffers -- the
// L2-hit (~200cyc) K load for tile ti+8 is in flight across the whole
// ti+4 half-iteration, so VALU/MFMA never wait on vmcnt.
// XCD swizzle: bh = (bid>>9)*8 + (bid&7) -> 4 bh per XCD, 2 MB working set.
__global__ __launch_bounds__(256)
void attn_diag_kernel(const u16* __restrict__ Q, const u16* __restrict__ Kp,
                      float* __restrict__ diag_p)
{
    __shared__ float lred[2][4][16];
    __shared__ float dred[2][4][16];
    const int bid = blockIdx.x;
    const int xcd = bid & 7;
    const int i   = bid >> 3;        // 0..255
    const int p   = i & 63;          // pair index
    const int bh  = ((i >> 6) << 3) + xcd;
    const int b = bh >> 4, h = bh & 15;
    const int wave = threadIdx.x >> 6, lane = threadIdx.x & 63;
    const int quad = lane >> 4, l16 = lane & 15;
    const int slo = p * 16;
    const int shi = (127 - p) * 16;

    // A-frags (Q): m = l16 (row), k = quad*8+j
    const u16* qlo = Q + ((size_t)(b * S_) + slo + l16) * E_ + h * D_ + quad * 8;
    const u16* qhi = Q + ((size_t)(b * S_) + shi + l16) * E_ + h * D_ + quad * 8;
    short8 alo0 = *(const short8*)(qlo);
    short8 alo1 = *(const short8*)(qlo + 32);
    short8 ahi0 = *(const short8*)(qhi);
    short8 ahi1 = *(const short8*)(qhi + 32);

    float llo[4] = {0.f,0.f,0.f,0.f}, dlo[4] = {0.f,0.f,0.f,0.f};
    float lhi[4] = {0.f,0.f,0.f,0.f}, dhi[4] = {0.f,0.f,0.f,0.f};
    const float CE = 0.04508422002778f;      // log2(e)/32

    const int tmax = 127 - p;                // tile index of hi diagonal
    const u16* kbase = Kp + ((size_t)(b * S_) + l16) * E_ + h * D_ + quad * 8;

    // compute one 16x16 score tile for both strips at tile index ti
    auto compute = [&](int ti, short8 k0, short8 k1) {
        f32x4 sch = (f32x4){0.f,0.f,0.f,0.f};
        sch = __builtin_amdgcn_mfma_f32_16x16x32_bf16(ahi0, k0, sch, 0, 0, 0);
        sch = __builtin_amdgcn_mfma_f32_16x16x32_bf16(ahi1, k1, sch, 0, 0, 0);
        if (ti < tmax) {
            #pragma unroll
            for (int r = 0; r < 4; ++r) lhi[r] += exp2f(sch[r] * CE);
        } else {
            #pragma unroll
            for (int r = 0; r < 4; ++r) {
                int sg = quad * 4 + r;
                float e = (l16 <= sg) ? exp2f(sch[r] * CE) : 0.f;
                lhi[r] += e;
                if (l16 == sg) dhi[r] = e;
            }
        }
        if (ti <= p) {
            f32x4 scl = (f32x4){0.f,0.f,0.f,0.f};
            scl = __builtin_amdgcn_mfma_f32_16x16x32_bf16(alo0, k0, scl, 0, 0, 0);
            scl = __builtin_amdgcn_mfma_f32_16x16x32_bf16(alo1, k1, scl, 0, 0, 0);
            if (ti < p) {
                #pragma unroll
                for (int r = 0; r < 4; ++r) llo[r] += exp2f(scl[r] * CE);
            } else {
                #pragma unroll
                for (int r = 0; r < 4; ++r) {
                    int sg = quad * 4 + r;
                    float e = (l16 <= sg) ? exp2f(scl[r] * CE) : 0.f;
                    llo[r] += e;
                    if (l16 == sg) dlo[r] = e;
                }
            }
        }
    };

    // pipeline: preload tiles (wave) and (wave+4); steady-state keeps 2 in flight
    short8 A0, A1, B0, B1;
    {
        const u16* ka = kbase + (size_t)(imin(wave, tmax) * 16) * E_;
        A0 = *(const short8*)ka; A1 = *(const short8*)(ka + 32);
        const u16* kb2 = kbase + (size_t)(imin(wave + 4, tmax) * 16) * E_;
        B0 = *(const short8*)kb2; B1 = *(const short8*)(kb2 + 32);
    }
    int ti = wave;
    while (ti <= tmax) {
        compute(ti, A0, A1);
        {   // prefetch ti+8 into the A buffers (consumed two steps later)
            const u16* kn = kbase + (size_t)(imin(ti + 8, tmax) * 16) * E_;
            A0 = *(const short8*)kn; A1 = *(const short8*)(kn + 32);
        }
        ti += 4;
        if (ti > tmax) break;
        compute(ti, B0, B1);
        {
            const u16* kn = kbase + (size_t)(imin(ti + 8, tmax) * 16) * E_;
            B0 = *(const short8*)kn; B1 = *(const short8*)(kn + 32);
        }
        ti += 4;
    }

    // sum-reduce across the 16 lanes sharing each score row
    #pragma unroll
    for (int r = 0; r < 4; ++r) {
        #pragma unroll
        for (int off = 1; off < 16; off <<= 1) {
            lhi[r] += __shfl_xor(lhi[r], off);
            dhi[r] += __shfl_xor(dhi[r], off);
            llo[r] += __shfl_xor(llo[r], off);
            dlo[r] += __shfl_xor(dlo[r], off);
        }
    }
    if (l16 == 0) {
        #pragma unroll
        for (int r = 0; r < 4; ++r) {
            lred[0][wave][quad * 4 + r] = llo[r];
            dred[0][wave][quad * 4 + r] = dlo[r];
            lred[1][wave][quad * 4 + r] = lhi[r];
            dred[1][wave][quad * 4 + r] = dhi[r];
        }
    }
    __syncthreads();
    if (threadIdx.x < 32) {
        int strip = threadIdx.x >> 4;        // 0 = lo, 1 = hi
        int row   = threadIdx.x & 15;
        float l = lred[strip][0][row] + lred[strip][1][row]
                + lred[strip][2][row] + lred[strip][3][row];
        float d = dred[strip][0][row] + dred[strip][1][row]
                + dred[strip][2][row] + dred[strip][3][row];
        int sbase = strip ? shi : slo;
        diag_p[(size_t)bh * S_ + sbase + row] = d / l;
    }
}

// ---------------- attn_flat = diag_p * V (elementwise, 8 bf16 per thread) ----------------
__global__ __launch_bounds__(256)
void scale_v_kernel(const u16* __restrict__ V, const float* __restrict__ diag_p,
                    u16* __restrict__ An)
{
    size_t i = (size_t)blockIdx.x * blockDim.x + threadIdx.x;
    size_t base = i * 8;                       // element offset into [B*S, E]
    int e = (int)(base & (E_ - 1));
    size_t bs = base >> 10;                    // b*S + s
    int h = e >> 6;
    int b = (int)(bs >> 11);
    int s = (int)(bs & (S_ - 1));
    float p = diag_p[(size_t)(b * H_ + h) * S_ + s];
    int4 pk = *(const int4*)(V + base);
    u16* u = (u16*)&pk;
    #pragma unroll
    for (int j = 0; j < 8; ++j) u[j] = f2b(b2f(u[j]) * p);
    *(int4*)(An + base) = pk;
}

extern "C" void kernel_launch(void* const* d_in, const int* in_sizes, int n_in,
                              void* d_out, int out_size, void* d_ws, size_t ws_size,
                              hipStream_t stream)
{
    const float* X  = (const float*)d_in[0];
    const float* Wq = (const float*)d_in[1];
    const float* Wk = (const float*)d_in[2];
    const float* Wv = (const float*)d_in[3];
    const float* Wo = (const float*)d_in[4];
    float* Out = (float*)d_out;

    u16* Xb  = (u16*)d_ws;
    u16* Wqb = Xb  + (size_t)M_ * E_;
    u16* Wkb = Wqb + (size_t)E_ * E_;
    u16* Wvb = Wkb + (size_t)E_ * E_;
    u16* Wob = Wvb + (size_t)E_ * E_;
    u16* Q   = Wob + (size_t)E_ * E_;
    u16* K   = Q   + (size_t)M_ * E_;
    u16* V   = K   + (size_t)M_ * E_;
    u16* An  = V   + (size_t)M_ * E_;
    float* diag_p = (float*)(An + (size_t)M_ * E_);

    dim3 blk(256);
    cvt_kernel<<<dim3(4096 + 4 * 1024), blk, 0, stream>>>(X, Wq, Wk, Wv, Wo,
                                                          Xb, Wqb, Wkb, Wvb, Wob);
    qkv_kernel<<<dim3(M_/BM, E_/BN, 3), blk, 0, stream>>>(Xb, Wqb, Wkb, Wvb, Q, K, V);
    attn_diag_kernel<<<dim3(2048), blk, 0, stream>>>(Q, K, diag_p);
    scale_v_kernel<<<dim3((M_*E_/8)/256), blk, 0, stream>>>(V, diag_p, An);
    out_kernel<<<dim3(M_/BM, E_/BN), blk, 0, stream>>>(An, Wob, V, Out);
}

// Round 6
// 192.011 us; speedup vs baseline: 1.0691x; 1.0691x over previous
//
#include <hip/hip_runtime.h>
#include <hip/hip_bf16.h>

#define B_ 2
#define S_ 2048
#define E_ 1024
#define H_ 16
#define D_ 64
#define M_ (B_*S_)   // 4096 rows

typedef unsigned short u16;
typedef __attribute__((ext_vector_type(8))) short short8;   // 8 bf16 (4 VGPRs)
typedef __attribute__((ext_vector_type(4))) short short4v;  // 4 bf16 (8 B)
typedef __attribute__((ext_vector_type(4))) float f32x4;    // 4 fp32 acc

__device__ __forceinline__ float b2f(u16 u) {
    union { float f; unsigned int i; } x; x.i = ((unsigned int)u) << 16; return x.f;
}
__device__ __forceinline__ u16 f2b(float f) {
    union { float f; unsigned int i; } x; x.f = f;
    unsigned int r = x.i + 0x7fffu + ((x.i >> 16) & 1u);   // RNE
    return (u16)(r >> 16);
}
__device__ __forceinline__ int imin(int a, int b) { return a < b ? a : b; }

// ---------------- fp32 -> bf16 bulk cast (X + 4 weight matrices) ----------------
__global__ __launch_bounds__(256)
void cvt_kernel(const float* __restrict__ X,
                const float* __restrict__ Wq, const float* __restrict__ Wk,
                const float* __restrict__ Wv, const float* __restrict__ Wo,
                u16* __restrict__ Xb, u16* __restrict__ Wqb, u16* __restrict__ Wkb,
                u16* __restrict__ Wvb, u16* __restrict__ Wob)
{
    int bid = blockIdx.x;
    const float* src; u16* dst; int blk;
    if (bid < 4096) { src = X; dst = Xb; blk = bid; }
    else {
        int w = (bid - 4096) >> 10;
        blk = (bid - 4096) & 1023;
        src = (w == 0) ? Wq : (w == 1) ? Wk : (w == 2) ? Wv : Wo;
        dst = (w == 0) ? Wqb : (w == 1) ? Wkb : (w == 2) ? Wvb : Wob;
    }
    size_t i4 = (size_t)blk * 256 + threadIdx.x;     // float4 index
    float4 v = ((const float4*)src)[i4];
    short4v o;
    o.x = (short)f2b(v.x); o.y = (short)f2b(v.y);
    o.z = (short)f2b(v.z); o.w = (short)f2b(v.w);
    *(short4v*)(dst + i4 * 4) = o;
}

// ---------------- GEMM: C[M,N] = A[M,K] @ B[N,K]^T (+ optional skip) ----------------
#define BM 128
#define BN 128
#define BK 32

__device__ __forceinline__ void stage2(const u16* __restrict__ gbase, u16* lds,
                                       int ldg, int wave, int lane)
{
    #pragma unroll
    for (int n = 0; n < 2; ++n) {
        int chunk = wave * 2 + n;            // 8 chunks of 16 rows; wave w: 2w, 2w+1
        int r = chunk * 16 + (lane >> 2);
        int slot = lane & 3;
        int c = slot ^ ((r >> 1) & 3);
        const u16* g = gbase + (size_t)r * ldg + c * 8;
        u16* l = lds + chunk * 512;          // wave-uniform base; HW adds lane*16B
        __builtin_amdgcn_global_load_lds(
            (const __attribute__((address_space(1))) unsigned int*)g,
            (__attribute__((address_space(3))) unsigned int*)l, 16, 0, 0);
    }
}

template<bool F32OUT>
__device__ __forceinline__ void gemm_bt_core(
    const u16* __restrict__ A, const u16* __restrict__ Bm,
    void* __restrict__ Cv, const u16* __restrict__ skip,
    int N, int Kd, int bm, int bn)
{
    __shared__ u16 lA[BM * BK];
    __shared__ u16 lB[BN * BK];
    const int tid  = threadIdx.x;
    const int wave = tid >> 6, lane = tid & 63;
    const int quad = lane >> 4, l16 = lane & 15;
    const int wm = (wave & 1) * 64, wn = (wave >> 1) * 64;

    f32x4 acc[4][4];
    #pragma unroll
    for (int i = 0; i < 4; ++i)
        #pragma unroll
        for (int j = 0; j < 4; ++j)
            acc[i][j] = (f32x4){0.f, 0.f, 0.f, 0.f};

    for (int k0 = 0; k0 < Kd; k0 += BK) {
        stage2(A  + (size_t)bm * Kd + k0, lA, Kd, wave, lane);
        stage2(Bm + (size_t)bn * Kd + k0, lB, Kd, wave, lane);
        __syncthreads();
        short8 af[4], bf[4];
        #pragma unroll
        for (int i = 0; i < 4; ++i) {
            int R = wm + i * 16 + l16;
            af[i] = *(const short8*)&lA[R * 32 + ((quad ^ ((R >> 1) & 3)) * 8)];
        }
        #pragma unroll
        for (int j = 0; j < 4; ++j) {
            int R = wn + j * 16 + l16;
            bf[j] = *(const short8*)&lB[R * 32 + ((quad ^ ((R >> 1) & 3)) * 8)];
        }
        #pragma unroll
        for (int i = 0; i < 4; ++i)
            #pragma unroll
            for (int j = 0; j < 4; ++j)
                acc[i][j] = __builtin_amdgcn_mfma_f32_16x16x32_bf16(af[i], bf[j], acc[i][j], 0, 0, 0);
        __syncthreads();
    }

    // epilogue: C/D layout col=lane&15, row=quad*4+reg
    #pragma unroll
    for (int i = 0; i < 4; ++i) {
        #pragma unroll
        for (int j = 0; j < 4; ++j) {
            int row0 = bm + wm + i * 16 + quad * 4;
            int col  = bn + wn + j * 16 + l16;
            #pragma unroll
            for (int r = 0; r < 4; ++r) {
                size_t idx = (size_t)(row0 + r) * N + col;
                float v = acc[i][j][r];
                if (skip) v += b2f(skip[idx]);
                if (F32OUT) ((float*)Cv)[idx] = v;
                else        ((u16*)Cv)[idx]   = f2b(v);
            }
        }
    }
}

__global__ __launch_bounds__(256, 3)
void qkv_kernel(const u16* __restrict__ X,
                const u16* __restrict__ Wq, const u16* __restrict__ Wk, const u16* __restrict__ Wv,
                u16* __restrict__ Q, u16* __restrict__ K, u16* __restrict__ V)
{
    const u16* W = (blockIdx.z == 0) ? Wq : (blockIdx.z == 1) ? Wk : Wv;
    u16* C = (blockIdx.z == 0) ? Q : (blockIdx.z == 1) ? K : V;
    gemm_bt_core<false>(X, W, C, nullptr, E_, E_, blockIdx.x * BM, blockIdx.y * BN);
}

__global__ __launch_bounds__(256, 3)
void out_kernel(const u16* __restrict__ An, const u16* __restrict__ Wo,
                const u16* __restrict__ V, float* __restrict__ Out)
{
    gemm_bt_core<true>(An, Wo, Out, V, E_, E_, blockIdx.x * BM, blockIdx.y * BN);
}

// ---------------- attention: diag of causal softmax ----------------
// Block = 8 strips {g+16j} of one bh (g = 0..15). 4 waves split t-tiles
// (ti % 4 == wave); each K-tile is loaded ONCE per block and feeds up to
// 8 strips (16 MFMA + 32 exp2 per 2KB load -> load latency hidden by
// compute, 8x less L2 traffic than strip-pair scheme).
// Strip j active at tile ti iff st_j >= ti; diagonal at ti == st_j.
// Work per block = 8g + 456 strip-tiles, tiles = g+113 -> balanced grid.
// l-sums reduced: 16-lane shfl -> LDS across 4 waves. Diag values written
// straight to LDS by the owning lane (wave g%4 owns all diag tiles).
// No max-subtraction: logits = q.k/32 have std ~0.25.
// XCD swizzle: bh = (bid>>6)*8 + (bid&7) -> 4 bh per XCD (~1 MB in L2).
__global__ __launch_bounds__(256, 2)
void attn_diag_kernel(const u16* __restrict__ Q, const u16* __restrict__ Kp,
                      float* __restrict__ diag_p)
{
    __shared__ float lred[4][8][16];
    __shared__ float dv[8][16];
    const int bid = blockIdx.x;
    const int xcd = bid & 7;
    const int i   = bid >> 3;        // 0..63
    const int g   = i & 15;          // strip-group
    const int bh  = ((i >> 4) << 3) + xcd;
    const int b = bh >> 4, h = bh & 15;
    const int wave = threadIdx.x >> 6, lane = threadIdx.x & 63;
    const int quad = lane >> 4, l16 = lane & 15;
    const float CE = 0.04508422002778f;      // log2(e)/32

    // Q A-frags for the 8 strips: m = l16 (row), k = quad*8+j
    short8 aq0[8], aq1[8];
    #pragma unroll
    for (int j = 0; j < 8; ++j) {
        const u16* qp = Q + ((size_t)(b * S_) + (g + 16 * j) * 16 + l16) * E_ + h * D_ + quad * 8;
        aq0[j] = *(const short8*)qp;
        aq1[j] = *(const short8*)(qp + 32);
    }

    float l[8][4];
    #pragma unroll
    for (int j = 0; j < 8; ++j)
        #pragma unroll
        for (int r = 0; r < 4; ++r) l[j][r] = 0.f;

    const int TMAX = g + 112;                // = st_7 = largest diag tile
    const u16* kcol = Kp + ((size_t)(b * S_) + l16) * E_ + h * D_ + quad * 8;

    short8 K0c, K1c;
    {
        const u16* ka = kcol + (size_t)(wave * 16) * E_;
        K0c = *(const short8*)ka; K1c = *(const short8*)(ka + 32);
    }
    for (int ti = wave; ti <= TMAX; ti += 4) {
        // scores for all active strips (uniform branches; j unrolled)
        f32x4 sc[8];
        #pragma unroll
        for (int j = 0; j < 8; ++j) {
            if (g + 16 * j >= ti) {
                f32x4 t = (f32x4){0.f,0.f,0.f,0.f};
                t = __builtin_amdgcn_mfma_f32_16x16x32_bf16(aq0[j], K0c, t, 0, 0, 0);
                t = __builtin_amdgcn_mfma_f32_16x16x32_bf16(aq1[j], K1c, t, 0, 0, 0);
                sc[j] = t;
            }
        }
        // issue next K-tile load; it stays in flight across the exp chain
        {
            const u16* ka = kcol + (size_t)(imin(ti + 4, TMAX) * 16) * E_;
            K0c = *(const short8*)ka; K1c = *(const short8*)(ka + 32);
        }
        // exp-accumulate
        #pragma unroll
        for (int j = 0; j < 8; ++j) {
            int st = g + 16 * j;
            if (st > ti) {                    // fully unmasked tile
                #pragma unroll
                for (int r = 0; r < 4; ++r) l[j][r] += exp2f(sc[j][r] * CE);
            } else if (st == ti) {            // diagonal tile of strip j
                #pragma unroll
                for (int r = 0; r < 4; ++r) {
                    int sg = quad * 4 + r;
                    float e = (l16 <= sg) ? exp2f(sc[j][r] * CE) : 0.f;
                    l[j][r] += e;
                    if (l16 == sg) dv[j][sg] = e;
                }
            }
        }
    }

    // 16-lane row-sum then cross-wave LDS reduction
    #pragma unroll
    for (int j = 0; j < 8; ++j)
        #pragma unroll
        for (int r = 0; r < 4; ++r) {
            float v = l[j][r];
            v += __shfl_xor(v, 1); v += __shfl_xor(v, 2);
            v += __shfl_xor(v, 4); v += __shfl_xor(v, 8);
            if (l16 == 0) lred[wave][j][quad * 4 + r] = v;
        }
    __syncthreads();
    if (threadIdx.x < 128) {
        int j = threadIdx.x >> 4, row = threadIdx.x & 15;
        float lsum = lred[0][j][row] + lred[1][j][row]
                   + lred[2][j][row] + lred[3][j][row];
        diag_p[(size_t)bh * S_ + (g + 16 * j) * 16 + row] = dv[j][row] / lsum;
    }
}

// ---------------- attn_flat = diag_p * V (elementwise, 8 bf16 per thread) ----------------
__global__ __launch_bounds__(256)
void scale_v_kernel(const u16* __restrict__ V, const float* __restrict__ diag_p,
                    u16* __restrict__ An)
{
    size_t i = (size_t)blockIdx.x * blockDim.x + threadIdx.x;
    size_t base = i * 8;                       // element offset into [B*S, E]
    int e = (int)(base & (E_ - 1));
    size_t bs = base >> 10;                    // b*S + s
    int h = e >> 6;
    int b = (int)(bs >> 11);
    int s = (int)(bs & (S_ - 1));
    float p = diag_p[(size_t)(b * H_ + h) * S_ + s];
    int4 pk = *(const int4*)(V + base);
    u16* u = (u16*)&pk;
    #pragma unroll
    for (int j = 0; j < 8; ++j) u[j] = f2b(b2f(u[j]) * p);
    *(int4*)(An + base) = pk;
}

extern "C" void kernel_launch(void* const* d_in, const int* in_sizes, int n_in,
                              void* d_out, int out_size, void* d_ws, size_t ws_size,
                              hipStream_t stream)
{
    const float* X  = (const float*)d_in[0];
    const float* Wq = (const float*)d_in[1];
    const float* Wk = (const float*)d_in[2];
    const float* Wv = (const float*)d_in[3];
    const float* Wo = (const float*)d_in[4];
    float* Out = (float*)d_out;

    u16* Xb  = (u16*)d_ws;
    u16* Wqb = Xb  + (size_t)M_ * E_;
    u16* Wkb = Wqb + (size_t)E_ * E_;
    u16* Wvb = Wkb + (size_t)E_ * E_;
    u16* Wob = Wvb + (size_t)E_ * E_;
    u16* Q   = Wob + (size_t)E_ * E_;
    u16* K   = Q   + (size_t)M_ * E_;
    u16* V   = K   + (size_t)M_ * E_;
    u16* An  = V   + (size_t)M_ * E_;
    float* diag_p = (float*)(An + (size_t)M_ * E_);

    dim3 blk(256);
    cvt_kernel<<<dim3(4096 + 4 * 1024), blk, 0, stream>>>(X, Wq, Wk, Wv, Wo,
                                                          Xb, Wqb, Wkb, Wvb, Wob);
    qkv_kernel<<<dim3(M_/BM, E_/BN, 3), blk, 0, stream>>>(Xb, Wqb, Wkb, Wvb, Q, K, V);
    attn_diag_kernel<<<dim3(512), blk, 0, stream>>>(Q, K, diag_p);
    scale_v_kernel<<<dim3((M_*E_/8)/256), blk, 0, stream>>>(V, diag_p, An);
    out_kernel<<<dim3(M_/BM, E_/BN), blk, 0, stream>>>(An, Wob, V, Out);
}

// Round 7
// 184.602 us; speedup vs baseline: 1.1120x; 1.0401x over previous
//
#include <hip/hip_runtime.h>
#include <hip/hip_bf16.h>

#define B_ 2
#define S_ 2048
#define E_ 1024
#define H_ 16
#define D_ 64
#define M_ (B_*S_)   // 4096 rows

typedef unsigned short u16;
typedef __attribute__((ext_vector_type(8))) short short8;   // 8 bf16 (4 VGPRs)
typedef __attribute__((ext_vector_type(4))) short short4v;  // 4 bf16 (8 B)
typedef __attribute__((ext_vector_type(4))) float f32x4;    // 4 fp32 acc

__device__ __forceinline__ float b2f(u16 u) {
    union { float f; unsigned int i; } x; x.i = ((unsigned int)u) << 16; return x.f;
}
__device__ __forceinline__ u16 f2b(float f) {
    union { float f; unsigned int i; } x; x.f = f;
    unsigned int r = x.i + 0x7fffu + ((x.i >> 16) & 1u);   // RNE
    return (u16)(r >> 16);
}
__device__ __forceinline__ int imin(int a, int b) { return a < b ? a : b; }

// raw v_exp_f32 (2^x). Inputs here are |x| < ~1, so no OCML fixups needed.
#if __has_builtin(__builtin_amdgcn_exp2f)
__device__ __forceinline__ float ex2(float x) { return __builtin_amdgcn_exp2f(x); }
#else
__device__ __forceinline__ float ex2(float x) {
    float r; asm("v_exp_f32 %0, %1" : "=v"(r) : "v"(x)); return r;
}
#endif

// ---------------- fp32 -> bf16 bulk cast (X + 4 weight matrices) ----------------
__global__ __launch_bounds__(256)
void cvt_kernel(const float* __restrict__ X,
                const float* __restrict__ Wq, const float* __restrict__ Wk,
                const float* __restrict__ Wv, const float* __restrict__ Wo,
                u16* __restrict__ Xb, u16* __restrict__ Wqb, u16* __restrict__ Wkb,
                u16* __restrict__ Wvb, u16* __restrict__ Wob)
{
    int bid = blockIdx.x;
    const float* src; u16* dst; int blk;
    if (bid < 4096) { src = X; dst = Xb; blk = bid; }
    else {
        int w = (bid - 4096) >> 10;
        blk = (bid - 4096) & 1023;
        src = (w == 0) ? Wq : (w == 1) ? Wk : (w == 2) ? Wv : Wo;
        dst = (w == 0) ? Wqb : (w == 1) ? Wkb : (w == 2) ? Wvb : Wob;
    }
    size_t i4 = (size_t)blk * 256 + threadIdx.x;     // float4 index
    float4 v = ((const float4*)src)[i4];
    short4v o;
    o.x = (short)f2b(v.x); o.y = (short)f2b(v.y);
    o.z = (short)f2b(v.z); o.w = (short)f2b(v.w);
    *(short4v*)(dst + i4 * 4) = o;
}

// ---------------- GEMM: C[M,N] = A[M,K] @ B[N,K]^T (+ optional skip) ----------------
#define BM 128
#define BN 128
#define BK 32

__device__ __forceinline__ void stage2(const u16* __restrict__ gbase, u16* lds,
                                       int ldg, int wave, int lane)
{
    #pragma unroll
    for (int n = 0; n < 2; ++n) {
        int chunk = wave * 2 + n;            // 8 chunks of 16 rows; wave w: 2w, 2w+1
        int r = chunk * 16 + (lane >> 2);
        int slot = lane & 3;
        int c = slot ^ ((r >> 1) & 3);
        const u16* g = gbase + (size_t)r * ldg + c * 8;
        u16* l = lds + chunk * 512;          // wave-uniform base; HW adds lane*16B
        __builtin_amdgcn_global_load_lds(
            (const __attribute__((address_space(1))) unsigned int*)g,
            (__attribute__((address_space(3))) unsigned int*)l, 16, 0, 0);
    }
}

template<bool F32OUT>
__device__ __forceinline__ void gemm_bt_core(
    const u16* __restrict__ A, const u16* __restrict__ Bm,
    void* __restrict__ Cv, const u16* __restrict__ skip,
    int N, int Kd, int bm, int bn)
{
    __shared__ u16 lA[BM * BK];
    __shared__ u16 lB[BN * BK];
    const int tid  = threadIdx.x;
    const int wave = tid >> 6, lane = tid & 63;
    const int quad = lane >> 4, l16 = lane & 15;
    const int wm = (wave & 1) * 64, wn = (wave >> 1) * 64;

    f32x4 acc[4][4];
    #pragma unroll
    for (int i = 0; i < 4; ++i)
        #pragma unroll
        for (int j = 0; j < 4; ++j)
            acc[i][j] = (f32x4){0.f, 0.f, 0.f, 0.f};

    for (int k0 = 0; k0 < Kd; k0 += BK) {
        stage2(A  + (size_t)bm * Kd + k0, lA, Kd, wave, lane);
        stage2(Bm + (size_t)bn * Kd + k0, lB, Kd, wave, lane);
        __syncthreads();
        short8 af[4], bf[4];
        #pragma unroll
        for (int i = 0; i < 4; ++i) {
            int R = wm + i * 16 + l16;
            af[i] = *(const short8*)&lA[R * 32 + ((quad ^ ((R >> 1) & 3)) * 8)];
        }
        #pragma unroll
        for (int j = 0; j < 4; ++j) {
            int R = wn + j * 16 + l16;
            bf[j] = *(const short8*)&lB[R * 32 + ((quad ^ ((R >> 1) & 3)) * 8)];
        }
        #pragma unroll
        for (int i = 0; i < 4; ++i)
            #pragma unroll
            for (int j = 0; j < 4; ++j)
                acc[i][j] = __builtin_amdgcn_mfma_f32_16x16x32_bf16(af[i], bf[j], acc[i][j], 0, 0, 0);
        __syncthreads();
    }

    // epilogue: C/D layout col=lane&15, row=quad*4+reg
    #pragma unroll
    for (int i = 0; i < 4; ++i) {
        #pragma unroll
        for (int j = 0; j < 4; ++j) {
            int row0 = bm + wm + i * 16 + quad * 4;
            int col  = bn + wn + j * 16 + l16;
            #pragma unroll
            for (int r = 0; r < 4; ++r) {
                size_t idx = (size_t)(row0 + r) * N + col;
                float v = acc[i][j][r];
                if (skip) v += b2f(skip[idx]);
                if (F32OUT) ((float*)Cv)[idx] = v;
                else        ((u16*)Cv)[idx]   = f2b(v);
            }
        }
    }
}

__global__ __launch_bounds__(256, 3)
void qkv_kernel(const u16* __restrict__ X,
                const u16* __restrict__ Wq, const u16* __restrict__ Wk, const u16* __restrict__ Wv,
                u16* __restrict__ Q, u16* __restrict__ K, u16* __restrict__ V)
{
    const u16* W = (blockIdx.z == 0) ? Wq : (blockIdx.z == 1) ? Wk : Wv;
    u16* C = (blockIdx.z == 0) ? Q : (blockIdx.z == 1) ? K : V;
    gemm_bt_core<false>(X, W, C, nullptr, E_, E_, blockIdx.x * BM, blockIdx.y * BN);
}

__global__ __launch_bounds__(256, 3)
void out_kernel(const u16* __restrict__ An, const u16* __restrict__ Wo,
                const u16* __restrict__ V, float* __restrict__ Out)
{
    gemm_bt_core<true>(An, Wo, Out, V, E_, E_, blockIdx.x * BM, blockIdx.y * BN);
}

// ---------------- attention: diag of causal softmax ----------------
// Block = 4 strips {g+32j} of one bh (g = 0..31). 4 waves split t-tiles
// (ti % 4 == wave); each K-tile loaded once per block, feeds up to 4 strips.
// 1024 blocks = 4 blocks/CU = 16 waves/CU (launch_bounds caps VGPR<=128).
// exp via raw v_exp_f32 (ex2) -- logits*log2e/32 is tiny, no fixups needed.
// No max-subtraction: logits = q.k/32 have std ~0.25.
// XCD swizzle: bh = (bid>>8)*8 + (bid&7) -> 4 bh per XCD (~2 MB in L2).
__global__ __launch_bounds__(256, 4)
void attn_diag_kernel(const u16* __restrict__ Q, const u16* __restrict__ Kp,
                      float* __restrict__ diag_p)
{
    __shared__ float lred[4][4][16];
    __shared__ float dv[4][16];
    const int bid = blockIdx.x;
    const int xcd = bid & 7;
    const int i   = bid >> 3;        // 0..127
    const int g   = i & 31;          // strip-group
    const int bh  = ((i >> 5) << 3) + xcd;
    const int b = bh >> 4, h = bh & 15;
    const int wave = threadIdx.x >> 6, lane = threadIdx.x & 63;
    const int quad = lane >> 4, l16 = lane & 15;
    const float CE = 0.04508422002778f;      // log2(e)/32

    // Q A-frags for the 4 strips: m = l16 (row), k = quad*8+j
    short8 aq0[4], aq1[4];
    #pragma unroll
    for (int j = 0; j < 4; ++j) {
        const u16* qp = Q + ((size_t)(b * S_) + (g + 32 * j) * 16 + l16) * E_ + h * D_ + quad * 8;
        aq0[j] = *(const short8*)qp;
        aq1[j] = *(const short8*)(qp + 32);
    }

    float l[4][4];
    #pragma unroll
    for (int j = 0; j < 4; ++j)
        #pragma unroll
        for (int r = 0; r < 4; ++r) l[j][r] = 0.f;

    const int TMAX = g + 96;                 // = st_3 = largest diag tile
    const u16* kcol = Kp + ((size_t)(b * S_) + l16) * E_ + h * D_ + quad * 8;

    short8 K0c, K1c;
    {
        const u16* ka = kcol + (size_t)(wave * 16) * E_;
        K0c = *(const short8*)ka; K1c = *(const short8*)(ka + 32);
    }
    for (int ti = wave; ti <= TMAX; ti += 4) {
        // scores for all active strips (wave-uniform branches)
        f32x4 sc[4];
        #pragma unroll
        for (int j = 0; j < 4; ++j) {
            if (g + 32 * j >= ti) {
                f32x4 t = (f32x4){0.f,0.f,0.f,0.f};
                t = __builtin_amdgcn_mfma_f32_16x16x32_bf16(aq0[j], K0c, t, 0, 0, 0);
                t = __builtin_amdgcn_mfma_f32_16x16x32_bf16(aq1[j], K1c, t, 0, 0, 0);
                sc[j] = t;
            }
        }
        // issue next K-tile load; stays in flight across the exp chain
        {
            const u16* ka = kcol + (size_t)(imin(ti + 4, TMAX) * 16) * E_;
            K0c = *(const short8*)ka; K1c = *(const short8*)(ka + 32);
        }
        // exp-accumulate
        #pragma unroll
        for (int j = 0; j < 4; ++j) {
            int st = g + 32 * j;
            if (st > ti) {                    // fully unmasked tile
                #pragma unroll
                for (int r = 0; r < 4; ++r) l[j][r] += ex2(sc[j][r] * CE);
            } else if (st == ti) {            // diagonal tile of strip j
                #pragma unroll
                for (int r = 0; r < 4; ++r) {
                    int sg = quad * 4 + r;
                    float e = (l16 <= sg) ? ex2(sc[j][r] * CE) : 0.f;
                    l[j][r] += e;
                    if (l16 == sg) dv[j][sg] = e;
                }
            }
        }
    }

    // 16-lane row-sum then cross-wave LDS reduction
    #pragma unroll
    for (int j = 0; j < 4; ++j)
        #pragma unroll
        for (int r = 0; r < 4; ++r) {
            float v = l[j][r];
            v += __shfl_xor(v, 1); v += __shfl_xor(v, 2);
            v += __shfl_xor(v, 4); v += __shfl_xor(v, 8);
            if (l16 == 0) lred[wave][j][quad * 4 + r] = v;
        }
    __syncthreads();
    if (threadIdx.x < 64) {
        int j = threadIdx.x >> 4, row = threadIdx.x & 15;
        float lsum = lred[0][j][row] + lred[1][j][row]
                   + lred[2][j][row] + lred[3][j][row];
        diag_p[(size_t)bh * S_ + (g + 32 * j) * 16 + row] = dv[j][row] / lsum;
    }
}

// ---------------- attn_flat = diag_p * V (elementwise, 8 bf16 per thread) ----------------
__global__ __launch_bounds__(256)
void scale_v_kernel(const u16* __restrict__ V, const float* __restrict__ diag_p,
                    u16* __restrict__ An)
{
    size_t i = (size_t)blockIdx.x * blockDim.x + threadIdx.x;
    size_t base = i * 8;                       // element offset into [B*S, E]
    int e = (int)(base & (E_ - 1));
    size_t bs = base >> 10;                    // b*S + s
    int h = e >> 6;
    int b = (int)(bs >> 11);
    int s = (int)(bs & (S_ - 1));
    float p = diag_p[(size_t)(b * H_ + h) * S_ + s];
    int4 pk = *(const int4*)(V + base);
    u16* u = (u16*)&pk;
    #pragma unroll
    for (int j = 0; j < 8; ++j) u[j] = f2b(b2f(u[j]) * p);
    *(int4*)(An + base) = pk;
}

extern "C" void kernel_launch(void* const* d_in, const int* in_sizes, int n_in,
                              void* d_out, int out_size, void* d_ws, size_t ws_size,
                              hipStream_t stream)
{
    const float* X  = (const float*)d_in[0];
    const float* Wq = (const float*)d_in[1];
    const float* Wk = (const float*)d_in[2];
    const float* Wv = (const float*)d_in[3];
    const float* Wo = (const float*)d_in[4];
    float* Out = (float*)d_out;

    u16* Xb  = (u16*)d_ws;
    u16* Wqb = Xb  + (size_t)M_ * E_;
    u16* Wkb = Wqb + (size_t)E_ * E_;
    u16* Wvb = Wkb + (size_t)E_ * E_;
    u16* Wob = Wvb + (size_t)E_ * E_;
    u16* Q   = Wob + (size_t)E_ * E_;
    u16* K   = Q   + (size_t)M_ * E_;
    u16* V   = K   + (size_t)M_ * E_;
    u16* An  = V   + (size_t)M_ * E_;
    float* diag_p = (float*)(An + (size_t)M_ * E_);

    dim3 blk(256);
    cvt_kernel<<<dim3(4096 + 4 * 1024), blk, 0, stream>>>(X, Wq, Wk, Wv, Wo,
                                                          Xb, Wqb, Wkb, Wvb, Wob);
    qkv_kernel<<<dim3(M_/BM, E_/BN, 3), blk, 0, stream>>>(Xb, Wqb, Wkb, Wvb, Q, K, V);
    attn_diag_kernel<<<dim3(1024), blk, 0, stream>>>(Q, K, diag_p);
    scale_v_kernel<<<dim3((M_*E_/8)/256), blk, 0, stream>>>(V, diag_p, An);
    out_kernel<<<dim3(M_/BM, E_/BN), blk, 0, stream>>>(An, Wob, V, Out);
}

// Round 8
// 183.766 us; speedup vs baseline: 1.1171x; 1.0046x over previous
//
#include <hip/hip_runtime.h>
#include <hip/hip_bf16.h>

#define B_ 2
#define S_ 2048
#define E_ 1024
#define H_ 16
#define D_ 64
#define M_ (B_*S_)   // 4096 rows

typedef unsigned short u16;
typedef __attribute__((ext_vector_type(8))) short short8;   // 8 bf16 (4 VGPRs)
typedef __attribute__((ext_vector_type(4))) short short4v;  // 4 bf16 (8 B)
typedef __attribute__((ext_vector_type(4))) float f32x4;    // 4 fp32 acc

__device__ __forceinline__ float b2f(u16 u) {
    union { float f; unsigned int i; } x; x.i = ((unsigned int)u) << 16; return x.f;
}
__device__ __forceinline__ u16 f2b(float f) {
    union { float f; unsigned int i; } x; x.f = f;
    unsigned int r = x.i + 0x7fffu + ((x.i >> 16) & 1u);   // RNE
    return (u16)(r >> 16);
}
__device__ __forceinline__ int imin(int a, int b) { return a < b ? a : b; }

// raw v_exp_f32 (2^x). Inputs here are |x| < ~1, so no OCML fixups needed.
#if __has_builtin(__builtin_amdgcn_exp2f)
__device__ __forceinline__ float ex2(float x) { return __builtin_amdgcn_exp2f(x); }
#else
__device__ __forceinline__ float ex2(float x) {
    float r; asm("v_exp_f32 %0, %1" : "=v"(r) : "v"(x)); return r;
}
#endif

// ---------------- fp32 -> bf16 bulk cast (X + 4 weight matrices) ----------------
__global__ __launch_bounds__(256)
void cvt_kernel(const float* __restrict__ X,
                const float* __restrict__ Wq, const float* __restrict__ Wk,
                const float* __restrict__ Wv, const float* __restrict__ Wo,
                u16* __restrict__ Xb, u16* __restrict__ Wqb, u16* __restrict__ Wkb,
                u16* __restrict__ Wvb, u16* __restrict__ Wob)
{
    int bid = blockIdx.x;
    const float* src; u16* dst; int blk;
    if (bid < 4096) { src = X; dst = Xb; blk = bid; }
    else {
        int w = (bid - 4096) >> 10;
        blk = (bid - 4096) & 1023;
        src = (w == 0) ? Wq : (w == 1) ? Wk : (w == 2) ? Wv : Wo;
        dst = (w == 0) ? Wqb : (w == 1) ? Wkb : (w == 2) ? Wvb : Wob;
    }
    size_t i4 = (size_t)blk * 256 + threadIdx.x;     // float4 index
    float4 v = ((const float4*)src)[i4];
    short4v o;
    o.x = (short)f2b(v.x); o.y = (short)f2b(v.y);
    o.z = (short)f2b(v.z); o.w = (short)f2b(v.w);
    *(short4v*)(dst + i4 * 4) = o;
}

// ---------------- GEMM: C[M,N] = A[M,K] @ B[N,K]^T (+ optional skip) ----------------
// LDS rows of 32 shorts (4 x 16B slots), XOR slot swizzle absorbed into the
// global source address so global_load_lds's lane-linear DMA gives 2-way-max
// bank conflicts on ds_read_b128 (2-way is free).
#define BN 128
#define BK 32

template<int CH>   // chunks (16 rows) staged per wave
__device__ __forceinline__ void stage2(const u16* __restrict__ gbase, u16* lds,
                                       int ldg, int wave, int lane)
{
    #pragma unroll
    for (int n = 0; n < CH; ++n) {
        int chunk = wave * CH + n;
        int r = chunk * 16 + (lane >> 2);
        int slot = lane & 3;
        int c = slot ^ ((r >> 1) & 3);
        const u16* g = gbase + (size_t)r * ldg + c * 8;
        u16* l = lds + chunk * 512;          // wave-uniform base; HW adds lane*16B
        __builtin_amdgcn_global_load_lds(
            (const __attribute__((address_space(1))) unsigned int*)g,
            (__attribute__((address_space(3))) unsigned int*)l, 16, 0, 0);
    }
}

template<bool F32OUT, int BMT>
__device__ __forceinline__ void gemm_bt_core(
    const u16* __restrict__ A, const u16* __restrict__ Bm,
    void* __restrict__ Cv, const u16* __restrict__ skip,
    int N, int Kd, int bm, int bn)
{
    constexpr int NI = BMT / 32;             // 16-row tiles per wave in m
    __shared__ u16 lA[BMT * BK];
    __shared__ u16 lB[BN * BK];
    const int tid  = threadIdx.x;
    const int wave = tid >> 6, lane = tid & 63;
    const int quad = lane >> 4, l16 = lane & 15;
    const int wm = (wave & 1) * (BMT / 2), wn = (wave >> 1) * 64;

    f32x4 acc[NI][4];
    #pragma unroll
    for (int i = 0; i < NI; ++i)
        #pragma unroll
        for (int j = 0; j < 4; ++j)
            acc[i][j] = (f32x4){0.f, 0.f, 0.f, 0.f};

    for (int k0 = 0; k0 < Kd; k0 += BK) {
        stage2<BMT / 64>(A  + (size_t)bm * Kd + k0, lA, Kd, wave, lane);
        stage2<2>(Bm + (size_t)bn * Kd + k0, lB, Kd, wave, lane);
        __syncthreads();
        short8 af[NI], bf[4];
        #pragma unroll
        for (int i = 0; i < NI; ++i) {
            int R = wm + i * 16 + l16;
            af[i] = *(const short8*)&lA[R * 32 + ((quad ^ ((R >> 1) & 3)) * 8)];
        }
        #pragma unroll
        for (int j = 0; j < 4; ++j) {
            int R = wn + j * 16 + l16;
            bf[j] = *(const short8*)&lB[R * 32 + ((quad ^ ((R >> 1) & 3)) * 8)];
        }
        #pragma unroll
        for (int i = 0; i < NI; ++i)
            #pragma unroll
            for (int j = 0; j < 4; ++j)
                acc[i][j] = __builtin_amdgcn_mfma_f32_16x16x32_bf16(af[i], bf[j], acc[i][j], 0, 0, 0);
        __syncthreads();
    }

    // epilogue: C/D layout col=lane&15, row=quad*4+reg
    #pragma unroll
    for (int i = 0; i < NI; ++i) {
        #pragma unroll
        for (int j = 0; j < 4; ++j) {
            int row0 = bm + wm + i * 16 + quad * 4;
            int col  = bn + wn + j * 16 + l16;
            #pragma unroll
            for (int r = 0; r < 4; ++r) {
                size_t idx = (size_t)(row0 + r) * N + col;
                float v = acc[i][j][r];
                if (skip) v += b2f(skip[idx]);
                if (F32OUT) ((float*)Cv)[idx] = v;
                else        ((u16*)Cv)[idx]   = f2b(v);
            }
        }
    }
}

__global__ __launch_bounds__(256, 3)
void qkv_kernel(const u16* __restrict__ X,
                const u16* __restrict__ Wq, const u16* __restrict__ Wk, const u16* __restrict__ Wv,
                u16* __restrict__ Q, u16* __restrict__ K, u16* __restrict__ V)
{
    const u16* W = (blockIdx.z == 0) ? Wq : (blockIdx.z == 1) ? Wk : Wv;
    u16* C = (blockIdx.z == 0) ? Q : (blockIdx.z == 1) ? K : V;
    gemm_bt_core<false, 128>(X, W, C, nullptr, E_, E_, blockIdx.x * 128, blockIdx.y * BN);
}

// BM=64 -> 512 blocks = 2 blocks/CU so barrier drains overlap across blocks
__global__ __launch_bounds__(256, 4)
void out_kernel(const u16* __restrict__ An, const u16* __restrict__ Wo,
                const u16* __restrict__ V, float* __restrict__ Out)
{
    gemm_bt_core<true, 64>(An, Wo, Out, V, E_, E_, blockIdx.x * 64, blockIdx.y * BN);
}

// ---------------- attention: diag of causal softmax + fused V-scale ----------------
// Block = 8 strips {g+16j} of one bh (g = 0..15), 512 threads = 8 waves.
// Waves split t-tiles (ti % 8 == wave): per K-tile load -> up to 16 MFMA +
// 32 exp (high reuse), AND 16 waves/CU (4/SIMD) for latency hiding
// (launch_bounds(512,4) caps VGPR at 128; frags ~104).
// Diagonal tile of strip j is tile g+16j == g (mod 8) -> wave g&7 owns all
// diagonals. l-sums: 16-lane shfl then LDS across 8 waves. After reduction
// the block scales its own 128 V-rows x 64 h-cols by p = d/l and writes An
// (replaces the separate scale_v kernel; diag_p never hits global memory).
// No max-subtraction: logits = q.k/32 have std ~0.25 -> fp32 exp safe.
// XCD swizzle: 4 bh per XCD (~2 MB K+Q working set per XCD L2).
__global__ __launch_bounds__(512, 4)
void attn_diag_kernel(const u16* __restrict__ Q, const u16* __restrict__ Kp,
                      const u16* __restrict__ V, u16* __restrict__ An)
{
    __shared__ float lred[8][8][16];
    __shared__ float dv[8][16];
    __shared__ float pv[8][16];
    const int bid = blockIdx.x;      // 512 blocks
    const int xcd = bid & 7;
    const int i   = bid >> 3;        // 0..63
    const int g   = i & 15;          // strip-group
    const int bh  = ((i >> 4) << 3) + xcd;
    const int b = bh >> 4, h = bh & 15;
    const int wave = threadIdx.x >> 6, lane = threadIdx.x & 63;
    const int quad = lane >> 4, l16 = lane & 15;
    const float CE = 0.04508422002778f;      // log2(e)/32

    // Q A-frags for the 8 strips: m = l16 (row), k = quad*8+jj
    short8 aq0[8], aq1[8];
    #pragma unroll
    for (int j = 0; j < 8; ++j) {
        const u16* qp = Q + ((size_t)(b * S_) + (g + 16 * j) * 16 + l16) * E_ + h * D_ + quad * 8;
        aq0[j] = *(const short8*)qp;
        aq1[j] = *(const short8*)(qp + 32);
    }

    float l[8][4];
    #pragma unroll
    for (int j = 0; j < 8; ++j)
        #pragma unroll
        for (int r = 0; r < 4; ++r) l[j][r] = 0.f;

    const int TMAX = g + 112;                // largest diag tile (strip 7)
    const u16* kcol = Kp + ((size_t)(b * S_) + l16) * E_ + h * D_ + quad * 8;

    short8 K0c, K1c;
    {
        const u16* ka = kcol + (size_t)(wave * 16) * E_;
        K0c = *(const short8*)ka; K1c = *(const short8*)(ka + 32);
    }
    for (int ti = wave; ti <= TMAX; ti += 8) {
        // scores for active strips (wave-uniform branches)
        f32x4 sc[8];
        #pragma unroll
        for (int j = 0; j < 8; ++j) {
            if (g + 16 * j >= ti) {
                f32x4 t = (f32x4){0.f,0.f,0.f,0.f};
                t = __builtin_amdgcn_mfma_f32_16x16x32_bf16(aq0[j], K0c, t, 0, 0, 0);
                t = __builtin_amdgcn_mfma_f32_16x16x32_bf16(aq1[j], K1c, t, 0, 0, 0);
                sc[j] = t;
            }
        }
        // issue next K-tile load; stays in flight across the exp chain
        {
            const u16* ka = kcol + (size_t)(imin(ti + 8, TMAX) * 16) * E_;
            K0c = *(const short8*)ka; K1c = *(const short8*)(ka + 32);
        }
        // exp-accumulate
        #pragma unroll
        for (int j = 0; j < 8; ++j) {
            int st = g + 16 * j;
            if (st > ti) {                    // fully unmasked tile
                #pragma unroll
                for (int r = 0; r < 4; ++r) l[j][r] += ex2(sc[j][r] * CE);
            } else if (st == ti) {            // diagonal tile of strip j
                #pragma unroll
                for (int r = 0; r < 4; ++r) {
                    int sg = quad * 4 + r;
                    float e = (l16 <= sg) ? ex2(sc[j][r] * CE) : 0.f;
                    l[j][r] += e;
                    if (l16 == sg) dv[j][sg] = e;
                }
            }
        }
    }

    // 16-lane row-sum then cross-wave LDS reduction
    #pragma unroll
    for (int j = 0; j < 8; ++j)
        #pragma unroll
        for (int r = 0; r < 4; ++r) {
            float v = l[j][r];
            v += __shfl_xor(v, 1); v += __shfl_xor(v, 2);
            v += __shfl_xor(v, 4); v += __shfl_xor(v, 8);
            if (l16 == 0) lred[wave][j][quad * 4 + r] = v;
        }
    __syncthreads();
    if (threadIdx.x < 128) {
        int j = threadIdx.x >> 4, row = threadIdx.x & 15;
        float lsum = 0.f;
        #pragma unroll
        for (int w = 0; w < 8; ++w) lsum += lred[w][j][row];
        pv[j][row] = dv[j][row] / lsum;
    }
    __syncthreads();

    // fused V-scale: this block owns rows s = (g+16j)*16+r, cols h*64..h*64+63
    #pragma unroll
    for (int k = 0; k < 2; ++k) {
        int c = threadIdx.x + k * 512;       // 1024 chunks of 8 elems
        int row = c >> 3, col8 = (c & 7) * 8;
        int j = row >> 4, r = row & 15;
        int s = (g + 16 * j) * 16 + r;
        size_t idx = ((size_t)(b * S_) + s) * E_ + h * D_ + col8;
        float p = pv[j][r];
        int4 pk = *(const int4*)(V + idx);
        u16* u = (u16*)&pk;
        #pragma unroll
        for (int q = 0; q < 8; ++q) u[q] = f2b(b2f(u[q]) * p);
        *(int4*)(An + idx) = pk;
    }
}

extern "C" void kernel_launch(void* const* d_in, const int* in_sizes, int n_in,
                              void* d_out, int out_size, void* d_ws, size_t ws_size,
                              hipStream_t stream)
{
    const float* X  = (const float*)d_in[0];
    const float* Wq = (const float*)d_in[1];
    const float* Wk = (const float*)d_in[2];
    const float* Wv = (const float*)d_in[3];
    const float* Wo = (const float*)d_in[4];
    float* Out = (float*)d_out;

    u16* Xb  = (u16*)d_ws;
    u16* Wqb = Xb  + (size_t)M_ * E_;
    u16* Wkb = Wqb + (size_t)E_ * E_;
    u16* Wvb = Wkb + (size_t)E_ * E_;
    u16* Wob = Wvb + (size_t)E_ * E_;
    u16* Q   = Wob + (size_t)E_ * E_;
    u16* K   = Q   + (size_t)M_ * E_;
    u16* V   = K   + (size_t)M_ * E_;
    u16* An  = V   + (size_t)M_ * E_;

    cvt_kernel<<<dim3(4096 + 4 * 1024), dim3(256), 0, stream>>>(X, Wq, Wk, Wv, Wo,
                                                                Xb, Wqb, Wkb, Wvb, Wob);
    qkv_kernel<<<dim3(M_/128, E_/BN, 3), dim3(256), 0, stream>>>(Xb, Wqb, Wkb, Wvb, Q, K, V);
    attn_diag_kernel<<<dim3(512), dim3(512), 0, stream>>>(Q, K, V, An);
    out_kernel<<<dim3(M_/64, E_/BN), dim3(256), 0, stream>>>(An, Wob, V, Out);
}

// Round 10
// 161.065 us; speedup vs baseline: 1.2745x; 1.1409x over previous
//
#include <hip/hip_runtime.h>
#include <hip/hip_bf16.h>

#define B_ 2
#define S_ 2048
#define E_ 1024
#define H_ 16
#define D_ 64
#define M_ (B_*S_)   // 4096 rows

typedef unsigned short u16;
typedef __attribute__((ext_vector_type(8))) short short8;   // 8 bf16 (4 VGPRs)
typedef __attribute__((ext_vector_type(4))) short short4v;  // 4 bf16 (8 B)
typedef __attribute__((ext_vector_type(4))) float f32x4;    // 4 fp32 acc

__device__ __forceinline__ float b2f(u16 u) {
    union { float f; unsigned int i; } x; x.i = ((unsigned int)u) << 16; return x.f;
}
__device__ __forceinline__ u16 f2b(float f) {
    union { float f; unsigned int i; } x; x.f = f;
    unsigned int r = x.i + 0x7fffu + ((x.i >> 16) & 1u);   // RNE
    return (u16)(r >> 16);
}

// raw v_exp_f32 (2^x); inputs tiny (|x|<~1), no OCML fixups needed
#if __has_builtin(__builtin_amdgcn_exp2f)
__device__ __forceinline__ float ex2(float x) { return __builtin_amdgcn_exp2f(x); }
#else
__device__ __forceinline__ float ex2(float x) {
    float r; asm("v_exp_f32 %0, %1" : "=v"(r) : "v"(x)); return r;
}
#endif

// ---------------- fp32 -> bf16 bulk cast (+ zero the l-accumulator) ----------------
__global__ __launch_bounds__(256)
void cvt_kernel(const float* __restrict__ X,
                const float* __restrict__ Wq, const float* __restrict__ Wk,
                const float* __restrict__ Wv, const float* __restrict__ Wo,
                u16* __restrict__ Xb, u16* __restrict__ Wqb, u16* __restrict__ Wkb,
                u16* __restrict__ Wvb, u16* __restrict__ Wob,
                float* __restrict__ lsum)
{
    int bid = blockIdx.x;
    if (bid >= 8192) {                       // zero lsum: 64 blocks x 1024 floats
        size_t i4 = (size_t)(bid - 8192) * 256 + threadIdx.x;
        ((float4*)lsum)[i4] = make_float4(0.f, 0.f, 0.f, 0.f);
        return;
    }
    const float* src; u16* dst; int blk;
    if (bid < 4096) { src = X; dst = Xb; blk = bid; }
    else {
        int w = (bid - 4096) >> 10;
        blk = (bid - 4096) & 1023;
        src = (w == 0) ? Wq : (w == 1) ? Wk : (w == 2) ? Wv : Wo;
        dst = (w == 0) ? Wqb : (w == 1) ? Wkb : (w == 2) ? Wvb : Wob;
    }
    size_t i4 = (size_t)blk * 256 + threadIdx.x;     // float4 index
    float4 v = ((const float4*)src)[i4];
    short4v o;
    o.x = (short)f2b(v.x); o.y = (short)f2b(v.y);
    o.z = (short)f2b(v.z); o.w = (short)f2b(v.w);
    *(short4v*)(dst + i4 * 4) = o;
}

// ---------------- GEMM core: acc = A[M,K] @ B[N,K]^T tile ----------------
// LDS rows of 32 shorts (4 x 16B slots), XOR slot swizzle absorbed into the
// global source address so global_load_lds's lane-linear DMA gives 2-way-max
// bank conflicts on ds_read_b128 (2-way is free).
#define BN 128
#define BK 32

template<int CH>   // chunks (16 rows) staged per wave
__device__ __forceinline__ void stage2(const u16* __restrict__ gbase, u16* lds,
                                       int ldg, int wave, int lane)
{
    #pragma unroll
    for (int n = 0; n < CH; ++n) {
        int chunk = wave * CH + n;
        int r = chunk * 16 + (lane >> 2);
        int slot = lane & 3;
        int c = slot ^ ((r >> 1) & 3);
        const u16* g = gbase + (size_t)r * ldg + c * 8;
        u16* l = lds + chunk * 512;          // wave-uniform base; HW adds lane*16B
        __builtin_amdgcn_global_load_lds(
            (const __attribute__((address_space(1))) unsigned int*)g,
            (__attribute__((address_space(3))) unsigned int*)l, 16, 0, 0);
    }
}

template<int BMT>
__device__ __forceinline__ void gemm_bt_acc(
    const u16* __restrict__ A, const u16* __restrict__ Bm,
    int Kd, int bm, int bn, f32x4 (*acc)[4])
{
    constexpr int NI = BMT / 32;             // 16-row tiles per wave in m
    __shared__ u16 lA[BMT * BK];
    __shared__ u16 lB[BN * BK];
    const int tid  = threadIdx.x;
    const int wave = tid >> 6, lane = tid & 63;
    const int quad = lane >> 4, l16 = lane & 15;
    const int wm = (wave & 1) * (BMT / 2), wn = (wave >> 1) * 64;

    for (int k0 = 0; k0 < Kd; k0 += BK) {
        stage2<BMT / 64>(A  + (size_t)bm * Kd + k0, lA, Kd, wave, lane);
        stage2<2>(Bm + (size_t)bn * Kd + k0, lB, Kd, wave, lane);
        __syncthreads();
        short8 af[NI], bf[4];
        #pragma unroll
        for (int i = 0; i < NI; ++i) {
            int R = wm + i * 16 + l16;
            af[i] = *(const short8*)&lA[R * 32 + ((quad ^ ((R >> 1) & 3)) * 8)];
        }
        #pragma unroll
        for (int j = 0; j < 4; ++j) {
            int R = wn + j * 16 + l16;
            bf[j] = *(const short8*)&lB[R * 32 + ((quad ^ ((R >> 1) & 3)) * 8)];
        }
        #pragma unroll
        for (int i = 0; i < NI; ++i)
            #pragma unroll
            for (int j = 0; j < 4; ++j)
                acc[i][j] = __builtin_amdgcn_mfma_f32_16x16x32_bf16(af[i], bf[j], acc[i][j], 0, 0, 0);
        __syncthreads();
    }
}

__global__ __launch_bounds__(256, 3)
void qkv_kernel(const u16* __restrict__ X,
                const u16* __restrict__ Wq, const u16* __restrict__ Wk, const u16* __restrict__ Wv,
                u16* __restrict__ Q, u16* __restrict__ K, u16* __restrict__ V)
{
    const u16* W = (blockIdx.z == 0) ? Wq : (blockIdx.z == 1) ? Wk : Wv;
    u16* C = (blockIdx.z == 0) ? Q : (blockIdx.z == 1) ? K : V;
    const int bm = blockIdx.x * 128, bn = blockIdx.y * BN;
    f32x4 acc[4][4];
    #pragma unroll
    for (int i = 0; i < 4; ++i)
        #pragma unroll
        for (int j = 0; j < 4; ++j) acc[i][j] = (f32x4){0.f,0.f,0.f,0.f};
    gemm_bt_acc<128>(X, W, E_, bm, bn, acc);

    const int wave = threadIdx.x >> 6, lane = threadIdx.x & 63;
    const int quad = lane >> 4, l16 = lane & 15;
    const int wm = (wave & 1) * 64, wn = (wave >> 1) * 64;
    #pragma unroll
    for (int i = 0; i < 4; ++i)
        #pragma unroll
        for (int j = 0; j < 4; ++j) {
            int row0 = bm + wm + i * 16 + quad * 4;
            int col  = bn + wn + j * 16 + l16;
            #pragma unroll
            for (int r = 0; r < 4; ++r)
                C[(size_t)(row0 + r) * E_ + col] = f2b(acc[i][j][r]);
        }
}

// Out = An @ Wo^T + V  (An = per-head-scaled V; fp32 out)
__global__ __launch_bounds__(256, 4)
void out_kernel(const u16* __restrict__ An, const u16* __restrict__ Wo,
                const u16* __restrict__ V, float* __restrict__ Out)
{
    const int bm = blockIdx.x * 64, bn = blockIdx.y * BN;
    f32x4 acc[2][4];
    #pragma unroll
    for (int i = 0; i < 2; ++i)
        #pragma unroll
        for (int j = 0; j < 4; ++j) acc[i][j] = (f32x4){0.f,0.f,0.f,0.f};
    gemm_bt_acc<64>(An, Wo, E_, bm, bn, acc);

    const int wave = threadIdx.x >> 6, lane = threadIdx.x & 63;
    const int quad = lane >> 4, l16 = lane & 15;
    const int wm = (wave & 1) * 32, wn = (wave >> 1) * 64;
    #pragma unroll
    for (int i = 0; i < 2; ++i)
        #pragma unroll
        for (int j = 0; j < 4; ++j) {
            int row0 = bm + wm + i * 16 + quad * 4;
            int col  = bn + wn + j * 16 + l16;
            #pragma unroll
            for (int r = 0; r < 4; ++r) {
                size_t idx = (size_t)(row0 + r) * E_ + col;
                Out[idx] = acc[i][j][r] + b2f(V[idx]);
            }
        }
}

// ---------------- attention l-rowsums: tiled exp(QK^T/32) pass ----------------
// Block = one 128x128 causal score tile (ii,jj) of one bh; 4352 blocks = 17/CU.
// K-tile (128x64) staged in LDS as TWO stacked 128x32 GEMM-style planes
// (f = k-half) with the proven XOR slot swizzle -> 2-way-max bank conflicts.
// Each wave: 2 m-tiles x 8 n-tiles x K=64 -> 32 MFMAs, then exp + rowsum
// (mask + diag extraction on ii==jj blocks), one fp32 atomicAdd per row.
__global__ __launch_bounds__(256, 4)
void attn_tiles_kernel(const u16* __restrict__ Q, const u16* __restrict__ Kp,
                       float* __restrict__ lsum, float* __restrict__ ed)
{
    __shared__ u16 lK[128 * 64];             // 16 KB
    const int tau = blockIdx.x;              // 0..135 triangular tile index
    const int bh  = blockIdx.y;
    const int b = bh >> 4, h = bh & 15;
    int ii = 0;
    while ((ii + 1) * (ii + 2) / 2 <= tau) ++ii;
    const int jj = tau - ii * (ii + 1) / 2;
    const bool diag = (ii == jj);
    const int wave = threadIdx.x >> 6, lane = threadIdx.x & 63;
    const int quad = lane >> 4, l16 = lane & 15;
    const float CE = 0.04508422002778f;      // log2(e)/32

    // stage K rows jj*128..+127, cols h*64..+63 (1024 chunks, 4 rounds)
    const u16* kg = Kp + ((size_t)(b * S_) + jj * 128) * E_ + h * D_;
    #pragma unroll
    for (int m4 = 0; m4 < 4; ++m4) {
        int q = m4 * 256 + wave * 64 + lane;
        int slot = q & 3, hr = q >> 2;
        int f = hr >> 7, r = hr & 127;
        int c = f * 4 + (slot ^ ((r >> 1) & 3));
        const u16* g = kg + (size_t)r * E_ + c * 8;
        u16* l = lK + (size_t)(m4 * 256 + wave * 64) * 8;   // wave-uniform base
        __builtin_amdgcn_global_load_lds(
            (const __attribute__((address_space(1))) unsigned int*)g,
            (__attribute__((address_space(3))) unsigned int*)l, 16, 0, 0);
    }

    // Q A-frags direct from global: rows ii*128 + wave*32 + m*16 + l16
    short8 aq[2][2];
    #pragma unroll
    for (int m = 0; m < 2; ++m) {
        const u16* qp = Q + ((size_t)(b * S_) + ii * 128 + wave * 32 + m * 16 + l16) * E_
                        + h * D_ + quad * 8;
        aq[m][0] = *(const short8*)qp;
        aq[m][1] = *(const short8*)(qp + 32);
    }
    __syncthreads();

    f32x4 acc[2][8];
    #pragma unroll
    for (int m = 0; m < 2; ++m)
        #pragma unroll
        for (int n = 0; n < 8; ++n) acc[m][n] = (f32x4){0.f,0.f,0.f,0.f};

    #pragma unroll
    for (int nt = 0; nt < 8; ++nt) {
        int R = nt * 16 + l16;
        int sw = (R >> 1) & 3;
        short8 bk0 = *(const short8*)&lK[((0 * 128 + R) * 4 + (quad ^ sw)) * 8];
        short8 bk1 = *(const short8*)&lK[((1 * 128 + R) * 4 + (quad ^ sw)) * 8];
        #pragma unroll
        for (int m = 0; m < 2; ++m) {
            acc[m][nt] = __builtin_amdgcn_mfma_f32_16x16x32_bf16(aq[m][0], bk0, acc[m][nt], 0, 0, 0);
            acc[m][nt] = __builtin_amdgcn_mfma_f32_16x16x32_bf16(aq[m][1], bk1, acc[m][nt], 0, 0, 0);
        }
    }

    // exp, (mask/diag on diagonal blocks), rowsum
    float rs[2][4];
    #pragma unroll
    for (int m = 0; m < 2; ++m)
        #pragma unroll
        for (int r = 0; r < 4; ++r) rs[m][r] = 0.f;

    #pragma unroll
    for (int m = 0; m < 2; ++m)
        #pragma unroll
        for (int nt = 0; nt < 8; ++nt)
            #pragma unroll
            for (int r = 0; r < 4; ++r) {
                float e = ex2(acc[m][nt][r] * CE);
                if (diag) {
                    int srow = wave * 32 + m * 16 + quad * 4 + r;   // within tile
                    int tcol = nt * 16 + l16;
                    if (tcol > srow) e = 0.f;
                    if (tcol == srow)
                        ed[(size_t)bh * S_ + ii * 128 + srow] = e;
                }
                rs[m][r] += e;
            }

    #pragma unroll
    for (int m = 0; m < 2; ++m)
        #pragma unroll
        for (int r = 0; r < 4; ++r) {
            float v = rs[m][r];
            v += __shfl_xor(v, 1); v += __shfl_xor(v, 2);
            v += __shfl_xor(v, 4); v += __shfl_xor(v, 8);
            if (l16 == 0) {
                int srow = ii * 128 + wave * 32 + m * 16 + quad * 4 + r;
                atomicAdd(&lsum[(size_t)bh * S_ + srow], v);
            }
        }
}

// ---------------- An = p * V, p = ed/lsum at (b, h(e), s) ----------------
__global__ __launch_bounds__(256)
void scale_v_kernel(const u16* __restrict__ V, const float* __restrict__ lsum,
                    const float* __restrict__ ed, u16* __restrict__ An)
{
    size_t i = (size_t)blockIdx.x * blockDim.x + threadIdx.x;
    size_t base = i * 8;                       // element offset into [B*S, E]
    int e = (int)(base & (E_ - 1));
    size_t bs = base >> 10;                    // b*S + s
    int h = e >> 6;
    int b = (int)(bs >> 11);
    int s = (int)(bs & (S_ - 1));
    size_t li = ((size_t)(b * H_ + h)) * S_ + s;
    float p = ed[li] / lsum[li];
    int4 pk = *(const int4*)(V + base);
    u16* u = (u16*)&pk;
    #pragma unroll
    for (int j = 0; j < 8; ++j) u[j] = f2b(b2f(u[j]) * p);
    *(int4*)(An + base) = pk;
}

extern "C" void kernel_launch(void* const* d_in, const int* in_sizes, int n_in,
                              void* d_out, int out_size, void* d_ws, size_t ws_size,
                              hipStream_t stream)
{
    const float* X  = (const float*)d_in[0];
    const float* Wq = (const float*)d_in[1];
    const float* Wk = (const float*)d_in[2];
    const float* Wv = (const float*)d_in[3];
    const float* Wo = (const float*)d_in[4];
    float* Out = (float*)d_out;

    u16* Xb  = (u16*)d_ws;
    u16* Wqb = Xb  + (size_t)M_ * E_;
    u16* Wkb = Wqb + (size_t)E_ * E_;
    u16* Wvb = Wkb + (size_t)E_ * E_;
    u16* Wob = Wvb + (size_t)E_ * E_;
    u16* Q   = Wob + (size_t)E_ * E_;
    u16* K   = Q   + (size_t)M_ * E_;
    u16* V   = K   + (size_t)M_ * E_;
    u16* An  = V   + (size_t)M_ * E_;
    float* lsum = (float*)(An + (size_t)M_ * E_);    // [32][2048] fp32
    float* ed   = lsum + (size_t)B_ * H_ * S_;       // [32][2048] fp32

    cvt_kernel<<<dim3(8192 + 64), dim3(256), 0, stream>>>(X, Wq, Wk, Wv, Wo,
                                                          Xb, Wqb, Wkb, Wvb, Wob, lsum);
    qkv_kernel<<<dim3(M_/128, E_/BN, 3), dim3(256), 0, stream>>>(Xb, Wqb, Wkb, Wvb, Q, K, V);
    attn_tiles_kernel<<<dim3(136, B_*H_), dim3(256), 0, stream>>>(Q, K, lsum, ed);
    scale_v_kernel<<<dim3((M_*E_/8)/256), dim3(256), 0, stream>>>(V, lsum, ed, An);
    out_kernel<<<dim3(M_/64, E_/BN), dim3(256), 0, stream>>>(An, Wob, V, Out);
}

// Round 11
// 153.192 us; speedup vs baseline: 1.3400x; 1.0514x over previous
//
#include <hip/hip_runtime.h>
#include <hip/hip_bf16.h>

#define B_ 2
#define S_ 2048
#define E_ 1024
#define H_ 16
#define D_ 64
#define M_ (B_*S_)   // 4096 rows

typedef unsigned short u16;
typedef __attribute__((ext_vector_type(8))) short short8;   // 8 bf16 (4 VGPRs)
typedef __attribute__((ext_vector_type(4))) short short4v;  // 4 bf16 (8 B)
typedef __attribute__((ext_vector_type(4))) float f32x4;    // 4 fp32 acc

__device__ __forceinline__ float b2f(u16 u) {
    union { float f; unsigned int i; } x; x.i = ((unsigned int)u) << 16; return x.f;
}
__device__ __forceinline__ u16 f2b(float f) {
    union { float f; unsigned int i; } x; x.f = f;
    unsigned int r = x.i + 0x7fffu + ((x.i >> 16) & 1u);   // RNE
    return (u16)(r >> 16);
}

// raw v_exp_f32 (2^x); inputs tiny (|x|<~1), no OCML fixups needed
#if __has_builtin(__builtin_amdgcn_exp2f)
__device__ __forceinline__ float ex2(float x) { return __builtin_amdgcn_exp2f(x); }
#else
__device__ __forceinline__ float ex2(float x) {
    float r; asm("v_exp_f32 %0, %1" : "=v"(r) : "v"(x)); return r;
}
#endif

// ---------------- fp32 -> bf16 bulk cast (+ zero the l-accumulator) ----------------
__global__ __launch_bounds__(256)
void cvt_kernel(const float* __restrict__ X,
                const float* __restrict__ Wq, const float* __restrict__ Wk,
                const float* __restrict__ Wv, const float* __restrict__ Wo,
                u16* __restrict__ Xb, u16* __restrict__ Wqb, u16* __restrict__ Wkb,
                u16* __restrict__ Wvb, u16* __restrict__ Wob,
                float* __restrict__ lsum)
{
    int bid = blockIdx.x;
    if (bid >= 8192) {                       // zero lsum: 64 blocks x 1024 floats
        size_t i4 = (size_t)(bid - 8192) * 256 + threadIdx.x;
        ((float4*)lsum)[i4] = make_float4(0.f, 0.f, 0.f, 0.f);
        return;
    }
    const float* src; u16* dst; int blk;
    if (bid < 4096) { src = X; dst = Xb; blk = bid; }
    else {
        int w = (bid - 4096) >> 10;
        blk = (bid - 4096) & 1023;
        src = (w == 0) ? Wq : (w == 1) ? Wk : (w == 2) ? Wv : Wo;
        dst = (w == 0) ? Wqb : (w == 1) ? Wkb : (w == 2) ? Wvb : Wob;
    }
    size_t i4 = (size_t)blk * 256 + threadIdx.x;     // float4 index
    float4 v = ((const float4*)src)[i4];
    short4v o;
    o.x = (short)f2b(v.x); o.y = (short)f2b(v.y);
    o.z = (short)f2b(v.z); o.w = (short)f2b(v.w);
    *(short4v*)(dst + i4 * 4) = o;
}

// ---------------- GEMM core: acc = A[M,K] @ B[N,K]^T tile, BK=64 ----------------
// LDS rows of 64 shorts (128 B = 8 x 16B slots). Slot swizzle c' = c ^ ((r>>1)&7)
// absorbed into the global source address: the lane-linear global_load_lds DMA
// (8 lanes = one permuted 128B row = one coalesced segment) lands so that the
// 16-row fragment ds_read_b128 sweeps all 8 slots (2 rows/slot = 2-way = free).
// BK=64 halves the s_barrier + vmcnt(0) drain count vs BK=32 (the m97-structure
// ~20% stall), at 2 MFMA k-steps per staged tile.
#define BN 128
#define BK 64

template<int ROWS>   // stages ROWS x 64 shorts with 4 waves
__device__ __forceinline__ void stage64(const u16* __restrict__ gbase, u16* lds,
                                        int ldg, int wave, int lane)
{
    constexpr int ITERS = ROWS * 8 / 256;    // 16B-chunks per thread
    #pragma unroll
    for (int n = 0; n < ITERS; ++n) {
        int q = (wave * ITERS + n) * 64 + lane;
        int r = q >> 3, slot = q & 7;
        int c = slot ^ ((r >> 1) & 7);
        const u16* g = gbase + (size_t)r * ldg + c * 8;
        u16* l = lds + (size_t)(wave * ITERS + n) * 512;   // wave-uniform base
        __builtin_amdgcn_global_load_lds(
            (const __attribute__((address_space(1))) unsigned int*)g,
            (__attribute__((address_space(3))) unsigned int*)l, 16, 0, 0);
    }
}

template<int BMT>
__device__ __forceinline__ void gemm_bt_acc(
    const u16* __restrict__ A, const u16* __restrict__ Bm,
    int Kd, int bm, int bn, f32x4 (*acc)[4])
{
    constexpr int NI = BMT / 32;             // 16-row tiles per wave in m
    __shared__ u16 lA[BMT * BK];
    __shared__ u16 lB[BN * BK];
    const int tid  = threadIdx.x;
    const int wave = tid >> 6, lane = tid & 63;
    const int quad = lane >> 4, l16 = lane & 15;
    const int wm = (wave & 1) * (BMT / 2), wn = (wave >> 1) * 64;

    for (int k0 = 0; k0 < Kd; k0 += BK) {
        stage64<BMT>(A  + (size_t)bm * Kd + k0, lA, Kd, wave, lane);
        stage64<BN>(Bm + (size_t)bn * Kd + k0, lB, Kd, wave, lane);
        __syncthreads();
        #pragma unroll
        for (int s = 0; s < 2; ++s) {        // two K=32 sub-steps per staged tile
            short8 af[NI], bf[4];
            #pragma unroll
            for (int i = 0; i < NI; ++i) {
                int R = wm + i * 16 + l16;
                int sc = s * 4 + quad;
                af[i] = *(const short8*)&lA[R * 64 + ((sc ^ ((R >> 1) & 7)) * 8)];
            }
            #pragma unroll
            for (int j = 0; j < 4; ++j) {
                int R = wn + j * 16 + l16;
                int sc = s * 4 + quad;
                bf[j] = *(const short8*)&lB[R * 64 + ((sc ^ ((R >> 1) & 7)) * 8)];
            }
            #pragma unroll
            for (int i = 0; i < NI; ++i)
                #pragma unroll
                for (int j = 0; j < 4; ++j)
                    acc[i][j] = __builtin_amdgcn_mfma_f32_16x16x32_bf16(af[i], bf[j], acc[i][j], 0, 0, 0);
        }
        __syncthreads();
    }
}

__global__ __launch_bounds__(256, 3)
void qkv_kernel(const u16* __restrict__ X,
                const u16* __restrict__ Wq, const u16* __restrict__ Wk, const u16* __restrict__ Wv,
                u16* __restrict__ Q, u16* __restrict__ K, u16* __restrict__ V)
{
    const u16* W = (blockIdx.z == 0) ? Wq : (blockIdx.z == 1) ? Wk : Wv;
    u16* C = (blockIdx.z == 0) ? Q : (blockIdx.z == 1) ? K : V;
    const int bm = blockIdx.x * 128, bn = blockIdx.y * BN;
    f32x4 acc[4][4];
    #pragma unroll
    for (int i = 0; i < 4; ++i)
        #pragma unroll
        for (int j = 0; j < 4; ++j) acc[i][j] = (f32x4){0.f,0.f,0.f,0.f};
    gemm_bt_acc<128>(X, W, E_, bm, bn, acc);

    const int wave = threadIdx.x >> 6, lane = threadIdx.x & 63;
    const int quad = lane >> 4, l16 = lane & 15;
    const int wm = (wave & 1) * 64, wn = (wave >> 1) * 64;
    #pragma unroll
    for (int i = 0; i < 4; ++i)
        #pragma unroll
        for (int j = 0; j < 4; ++j) {
            int row0 = bm + wm + i * 16 + quad * 4;
            int col  = bn + wn + j * 16 + l16;
            #pragma unroll
            for (int r = 0; r < 4; ++r)
                C[(size_t)(row0 + r) * E_ + col] = f2b(acc[i][j][r]);
        }
}

// Out = An @ Wo^T + V  (An = per-head-scaled V; fp32 out)
__global__ __launch_bounds__(256, 4)
void out_kernel(const u16* __restrict__ An, const u16* __restrict__ Wo,
                const u16* __restrict__ V, float* __restrict__ Out)
{
    const int bm = blockIdx.x * 64, bn = blockIdx.y * BN;
    f32x4 acc[2][4];
    #pragma unroll
    for (int i = 0; i < 2; ++i)
        #pragma unroll
        for (int j = 0; j < 4; ++j) acc[i][j] = (f32x4){0.f,0.f,0.f,0.f};
    gemm_bt_acc<64>(An, Wo, E_, bm, bn, acc);

    const int wave = threadIdx.x >> 6, lane = threadIdx.x & 63;
    const int quad = lane >> 4, l16 = lane & 15;
    const int wm = (wave & 1) * 32, wn = (wave >> 1) * 64;
    #pragma unroll
    for (int i = 0; i < 2; ++i)
        #pragma unroll
        for (int j = 0; j < 4; ++j) {
            int row0 = bm + wm + i * 16 + quad * 4;
            int col  = bn + wn + j * 16 + l16;
            #pragma unroll
            for (int r = 0; r < 4; ++r) {
                size_t idx = (size_t)(row0 + r) * E_ + col;
                Out[idx] = acc[i][j][r] + b2f(V[idx]);
            }
        }
}

// ---------------- attention l-rowsums: tiled exp(QK^T/32) pass ----------------
// Block = one 128x128 causal score tile (ii,jj) of one bh; 4352 blocks = 17/CU.
// K-tile (128x64) staged in LDS as TWO stacked 128x32 planes (f = k-half)
// with the 4-slot XOR swizzle -> 2-way-max bank conflicts.
// Each wave: 2 m-tiles x 8 n-tiles x K=64 -> 32 MFMAs, then exp + rowsum
// (mask + diag extraction on ii==jj blocks), one fp32 atomicAdd per row.
__global__ __launch_bounds__(256, 4)
void attn_tiles_kernel(const u16* __restrict__ Q, const u16* __restrict__ Kp,
                       float* __restrict__ lsum, float* __restrict__ ed)
{
    __shared__ u16 lK[128 * 64];             // 16 KB
    const int tau = blockIdx.x;              // 0..135 triangular tile index
    const int bh  = blockIdx.y;
    const int b = bh >> 4, h = bh & 15;
    int ii = 0;
    while ((ii + 1) * (ii + 2) / 2 <= tau) ++ii;
    const int jj = tau - ii * (ii + 1) / 2;
    const bool diag = (ii == jj);
    const int wave = threadIdx.x >> 6, lane = threadIdx.x & 63;
    const int quad = lane >> 4, l16 = lane & 15;
    const float CE = 0.04508422002778f;      // log2(e)/32

    // stage K rows jj*128..+127, cols h*64..+63 (1024 chunks, 4 rounds)
    const u16* kg = Kp + ((size_t)(b * S_) + jj * 128) * E_ + h * D_;
    #pragma unroll
    for (int m4 = 0; m4 < 4; ++m4) {
        int q = m4 * 256 + wave * 64 + lane;
        int slot = q & 3, hr = q >> 2;
        int f = hr >> 7, r = hr & 127;
        int c = f * 4 + (slot ^ ((r >> 1) & 3));
        const u16* g = kg + (size_t)r * E_ + c * 8;
        u16* l = lK + (size_t)(m4 * 256 + wave * 64) * 8;   // wave-uniform base
        __builtin_amdgcn_global_load_lds(
            (const __attribute__((address_space(1))) unsigned int*)g,
            (__attribute__((address_space(3))) unsigned int*)l, 16, 0, 0);
    }

    // Q A-frags direct from global: rows ii*128 + wave*32 + m*16 + l16
    short8 aq[2][2];
    #pragma unroll
    for (int m = 0; m < 2; ++m) {
        const u16* qp = Q + ((size_t)(b * S_) + ii * 128 + wave * 32 + m * 16 + l16) * E_
                        + h * D_ + quad * 8;
        aq[m][0] = *(const short8*)qp;
        aq[m][1] = *(const short8*)(qp + 32);
    }
    __syncthreads();

    f32x4 acc[2][8];
    #pragma unroll
    for (int m = 0; m < 2; ++m)
        #pragma unroll
        for (int n = 0; n < 8; ++n) acc[m][n] = (f32x4){0.f,0.f,0.f,0.f};

    #pragma unroll
    for (int nt = 0; nt < 8; ++nt) {
        int R = nt * 16 + l16;
        int sw = (R >> 1) & 3;
        short8 bk0 = *(const short8*)&lK[((0 * 128 + R) * 4 + (quad ^ sw)) * 8];
        short8 bk1 = *(const short8*)&lK[((1 * 128 + R) * 4 + (quad ^ sw)) * 8];
        #pragma unroll
        for (int m = 0; m < 2; ++m) {
            acc[m][nt] = __builtin_amdgcn_mfma_f32_16x16x32_bf16(aq[m][0], bk0, acc[m][nt], 0, 0, 0);
            acc[m][nt] = __builtin_amdgcn_mfma_f32_16x16x32_bf16(aq[m][1], bk1, acc[m][nt], 0, 0, 0);
        }
    }

    // exp, (mask/diag on diagonal blocks), rowsum
    float rs[2][4];
    #pragma unroll
    for (int m = 0; m < 2; ++m)
        #pragma unroll
        for (int r = 0; r < 4; ++r) rs[m][r] = 0.f;

    #pragma unroll
    for (int m = 0; m < 2; ++m)
        #pragma unroll
        for (int nt = 0; nt < 8; ++nt)
            #pragma unroll
            for (int r = 0; r < 4; ++r) {
                float e = ex2(acc[m][nt][r] * CE);
                if (diag) {
                    int srow = wave * 32 + m * 16 + quad * 4 + r;   // within tile
                    int tcol = nt * 16 + l16;
                    if (tcol > srow) e = 0.f;
                    if (tcol == srow)
                        ed[(size_t)bh * S_ + ii * 128 + srow] = e;
                }
                rs[m][r] += e;
            }

    #pragma unroll
    for (int m = 0; m < 2; ++m)
        #pragma unroll
        for (int r = 0; r < 4; ++r) {
            float v = rs[m][r];
            v += __shfl_xor(v, 1); v += __shfl_xor(v, 2);
            v += __shfl_xor(v, 4); v += __shfl_xor(v, 8);
            if (l16 == 0) {
                int srow = ii * 128 + wave * 32 + m * 16 + quad * 4 + r;
                atomicAdd(&lsum[(size_t)bh * S_ + srow], v);
            }
        }
}

// ---------------- An = p * V, p = ed/lsum at (b, h(e), s) ----------------
__global__ __launch_bounds__(256)
void scale_v_kernel(const u16* __restrict__ V, const float* __restrict__ lsum,
                    const float* __restrict__ ed, u16* __restrict__ An)
{
    size_t i = (size_t)blockIdx.x * blockDim.x + threadIdx.x;
    size_t base = i * 8;                       // element offset into [B*S, E]
    int e = (int)(base & (E_ - 1));
    size_t bs = base >> 10;                    // b*S + s
    int h = e >> 6;
    int b = (int)(bs >> 11);
    int s = (int)(bs & (S_ - 1));
    size_t li = ((size_t)(b * H_ + h)) * S_ + s;
    float p = ed[li] / lsum[li];
    int4 pk = *(const int4*)(V + base);
    u16* u = (u16*)&pk;
    #pragma unroll
    for (int j = 0; j < 8; ++j) u[j] = f2b(b2f(u[j]) * p);
    *(int4*)(An + base) = pk;
}

extern "C" void kernel_launch(void* const* d_in, const int* in_sizes, int n_in,
                              void* d_out, int out_size, void* d_ws, size_t ws_size,
                              hipStream_t stream)
{
    const float* X  = (const float*)d_in[0];
    const float* Wq = (const float*)d_in[1];
    const float* Wk = (const float*)d_in[2];
    const float* Wv = (const float*)d_in[3];
    const float* Wo = (const float*)d_in[4];
    float* Out = (float*)d_out;

    u16* Xb  = (u16*)d_ws;
    u16* Wqb = Xb  + (size_t)M_ * E_;
    u16* Wkb = Wqb + (size_t)E_ * E_;
    u16* Wvb = Wkb + (size_t)E_ * E_;
    u16* Wob = Wvb + (size_t)E_ * E_;
    u16* Q   = Wob + (size_t)E_ * E_;
    u16* K   = Q   + (size_t)M_ * E_;
    u16* V   = K   + (size_t)M_ * E_;
    u16* An  = V   + (size_t)M_ * E_;
    float* lsum = (float*)(An + (size_t)M_ * E_);    // [32][2048] fp32
    float* ed   = lsum + (size_t)B_ * H_ * S_;       // [32][2048] fp32

    cvt_kernel<<<dim3(8192 + 64), dim3(256), 0, stream>>>(X, Wq, Wk, Wv, Wo,
                                                          Xb, Wqb, Wkb, Wvb, Wob, lsum);
    qkv_kernel<<<dim3(M_/128, E_/BN, 3), dim3(256), 0, stream>>>(Xb, Wqb, Wkb, Wvb, Q, K, V);
    attn_tiles_kernel<<<dim3(136, B_*H_), dim3(256), 0, stream>>>(Q, K, lsum, ed);
    scale_v_kernel<<<dim3((M_*E_/8)/256), dim3(256), 0, stream>>>(V, lsum, ed, An);
    out_kernel<<<dim3(M_/64, E_/BN), dim3(256), 0, stream>>>(An, Wob, V, Out);
}